// Round 6
// baseline (463.970 us; speedup 1.0000x reference)
//
#include <hip/hip_runtime.h>
#include <hip/hip_bf16.h>

typedef __bf16 bf16_t;
typedef bf16_t bf16x8 __attribute__((ext_vector_type(8)));
typedef float  floatx4 __attribute__((ext_vector_type(4)));

#define NB    32
#define NV    207
#define NL    12
#define NROW  2484            // NV*NL rows per batch
#define TOTROW (NROW * NB)    // 79488
#define RPB   128             // rows per block (8 waves x 16)
#define NBLK  (TOTROW / RPB)  // 621 exactly, no tail
#define HSLICE 24576          // elems per head slice (12 mats x 16 rows x 128)

// ---- kernel 0: transpose + permute fp32 W[comp][d][e] -> bf16 wt in
// HEAD-SLICE FRAGMENT ORDER: wt[h*24576 + slot*8 + j], slot = mat*256 + k*64
// + quad*16 + l16, value = W[d = k*32+quad*8+j][e = h*16+l16].
// This makes the fused kernel's global staging address == its LDS offset.
__global__ __launch_bounds__(256)
void transpose_w(const float* __restrict__ wq,
                 const float* __restrict__ wk,
                 const float* __restrict__ wv,
                 bf16_t* __restrict__ wt) {
  __shared__ float t[32][33];
  const int mat  = blockIdx.x >> 4;          // 0..11
  const int tile = blockIdx.x & 15;          // 4x4 tiles of 32x32
  const int td = (tile >> 2) << 5;           // d-tile origin
  const int te = (tile & 3) << 5;            // e-tile origin
  const float* src = (mat < 4) ? wq : ((mat < 8) ? wk : wv);
  src += ((mat & 3) << 14);
  const int c  = threadIdx.x & 31;
  const int r0 = threadIdx.x >> 5;           // 0..7
#pragma unroll
  for (int rr = 0; rr < 4; ++rr) {
    const int r = r0 + (rr << 3);
    t[r][c] = src[((td + r) << 7) + te + c]; // read W[d][e], coalesced in e
  }
  __syncthreads();
#pragma unroll
  for (int rr = 0; rr < 4; ++rr) {
    const int r = r0 + (rr << 3);
    const int e = te + r, d = td + c;
    const int slot = (mat << 8) + ((d >> 5) << 6) + (((d >> 3) & 3) << 4) + (e & 15);
    wt[(e >> 4) * HSLICE + (slot << 3) + (d & 7)] = (bf16_t)t[c][r];
  }
}

__device__ __forceinline__ bf16x8 ldf8(const float* p) {
  floatx4 a = *(const floatx4*)p;
  floatx4 b = *(const floatx4*)(p + 4);
  bf16x8 r;
  r[0] = (bf16_t)a[0]; r[1] = (bf16_t)a[1]; r[2] = (bf16_t)a[2]; r[3] = (bf16_t)a[3];
  r[4] = (bf16_t)b[0]; r[5] = (bf16_t)b[1]; r[6] = (bf16_t)b[2]; r[7] = (bf16_t)b[3];
  return r;
}

__device__ __forceinline__ float bcast(float v) {
  return __uint_as_float(__builtin_amdgcn_readfirstlane(__float_as_uint(v)));
}

// global -> LDS direct (0 VGPRs), 16B per lane; dest is lane-linear (stride 16B).
__device__ __forceinline__ void stage16(const bf16_t* g, bf16_t* l) {
  __builtin_amdgcn_global_load_lds(
      (const __attribute__((address_space(1))) unsigned int*)g,
      (__attribute__((address_space(3))) unsigned int*)l, 16, 0, 0);
}

// Block = 8 waves x 16 rows = 128 rows, all 4 components, all 8 heads.
// x fragments in regs for the whole kernel (read ONCE). Per head: 48 KB
// fragment-ordered weight slice staged via global_load_lds, single buffer.
// amdgpu_waves_per_eu(4,4): clamp occupancy target at 4 waves/EU so the
// scheduler does NOT squeeze VGPRs to the 64 tier (rounds 4/5 failure:
// VGPR=64 -> scratch spills, WRITE_SIZE 287 MB vs 163 MB of real output).
__global__ __launch_bounds__(512)
__attribute__((amdgpu_waves_per_eu(4, 4)))
void fused_attn(const float* __restrict__ x,
                const bf16_t* __restrict__ wt,
                const float* __restrict__ bq,
                const float* __restrict__ bk,
                const float* __restrict__ bv,
                const float* __restrict__ aw,
                float* __restrict__ out) {
  __shared__ bf16_t wlds[HSLICE];            // 49152 B

  const int tid  = threadIdx.x;
  const int wid  = tid >> 6;
  const int lane = tid & 63;
  const int quad = lane >> 4;
  const int l16  = lane & 15;

  const int g = blockIdx.x * RPB + (wid << 4) + l16;   // global output row, < 79488
  const int b = g / NROW;
  const int n = g - b * NROW;
  const int v = n % NV;
  const int l = n / NV;
  const unsigned qkvbase = (((unsigned)b * NROW + (unsigned)(v * NL + l)) << 9); // attn source row
  const unsigned outbase = ((unsigned)g << 9);                                   // residual/store row

  // ---- x fragments for all 4 components, held in regs all kernel (64 VGPR) ----
  bf16x8 bx[4][4];
#pragma unroll
  for (int c = 0; c < 4; ++c) {
    const float* xp = x + qkvbase + (c << 7) + (quad << 3);
#pragma unroll
    for (int k = 0; k < 4; ++k) bx[c][k] = ldf8(xp + (k << 5));
  }

  // ---- stage head-0 slice: LDS offset == global offset (fragment order) ----
#pragma unroll
  for (int q = 0; q < 6; ++q) {
    const unsigned off = ((unsigned)tid << 3) + ((unsigned)q << 12);
    stage16(wt + off, &wlds[off]);
  }

  // ---- normalized subset weights (uniform -> SGPR) ----
  float pw[4][7];
#pragma unroll
  for (int i = 0; i < 4; ++i) {
    float sum = 0.f;
#pragma unroll
    for (int t = 0; t < 7; ++t) { pw[i][t] = __expf(aw[i * 8 + 1 + t]); sum += pw[i][t]; }
    const float inv = __builtin_amdgcn_rcpf(sum);
#pragma unroll
    for (int t = 0; t < 7; ++t) pw[i][t] = bcast(pw[i][t] * inv);
  }

  __syncthreads();   // drains vmcnt (gload_lds) then barrier

  const bf16_t* lbase = wlds + (lane << 3);

  // ---- head loop ----
  for (int h = 0; h < 8; ++h) {
    const int bofs = (h << 4) + (quad << 2);

    // ---- phase A: Q projections (mats 0..3) ----
    floatx4 QQ[4];
#pragma unroll
    for (int c = 0; c < 4; ++c) {
      floatx4 acc = *(const floatx4*)(bq + (c << 7) + bofs);
#pragma unroll
      for (int k = 0; k < 4; ++k)
        acc = __builtin_amdgcn_mfma_f32_16x16x32_bf16(
                *(const bf16x8*)(lbase + (((c << 2) + k) << 9)), bx[c][k], acc, 0, 0, 0);
      QQ[c] = acc;
    }

    // ---- phase B: stream K_j (mats 4..7), scores ee[i][j] ----
    float ee[4][4];
#pragma unroll
    for (int j = 0; j < 4; ++j) {
      floatx4 kk = *(const floatx4*)(bk + (j << 7) + bofs);
#pragma unroll
      for (int k = 0; k < 4; ++k)
        kk = __builtin_amdgcn_mfma_f32_16x16x32_bf16(
               *(const bf16x8*)(lbase + ((((4 + j) << 2) + k) << 9)), bx[j][k], kk, 0, 0, 0);
#pragma unroll
      for (int i = 0; i < 4; ++i) {
        if (i == j) continue;
        float p = QQ[i][0] * kk[0];
        p += QQ[i][1] * kk[1];
        p += QQ[i][2] * kk[2];
        p += QQ[i][3] * kk[3];
        p += __shfl_xor(p, 16);
        p += __shfl_xor(p, 32);
        ee[i][j] = __expf(p * 0.25f);
      }
    }

    // ---- phase C: subset-softmax coefficients cf[i][j] ----
    float cf[4][4];
#pragma unroll
    for (int i = 0; i < 4; ++i) {
      const int ja = (i == 0) ? 1 : 0;
      const int jb = (i < 2) ? 2 : 1;
      const int jc = (i < 3) ? 3 : 2;
      const float* w = pw[i];
      const float ea = ee[i][ja], eb = ee[i][jb], ec = ee[i][jc];
      const float dab = ea + eb, dac = ea + ec, dbc = eb + ec, dabc = dab + ec;
      const float r3 = w[2] * __builtin_amdgcn_rcpf(dbc);
      const float r5 = w[4] * __builtin_amdgcn_rcpf(dac);
      const float r6 = w[5] * __builtin_amdgcn_rcpf(dab);
      const float r7 = w[6] * __builtin_amdgcn_rcpf(dabc);
      cf[i][ja] = w[3] + ea * (r5 + r6 + r7);
      cf[i][jb] = w[1] + eb * (r3 + r6 + r7);
      cf[i][jc] = w[0] + ec * (r3 + r5 + r7);
    }

    // ---- phase D: residual load + stream V_j (mats 8..11), weighted combine ----
    // residual loads here (not at loop top): trims 16 regs of live range so
    // peak pressure stays under the 128-VGPR / 4-wave budget.
    floatx4 oacc[4];
#pragma unroll
    for (int i = 0; i < 4; ++i)
      oacc[i] = *(const floatx4*)(x + outbase + ((unsigned)i << 7) + (unsigned)bofs);

#pragma unroll
    for (int j = 0; j < 4; ++j) {
      floatx4 vv = *(const floatx4*)(bv + (j << 7) + bofs);
#pragma unroll
      for (int k = 0; k < 4; ++k)
        vv = __builtin_amdgcn_mfma_f32_16x16x32_bf16(
               *(const bf16x8*)(lbase + ((((8 + j) << 2) + k) << 9)), bx[j][k], vv, 0, 0, 0);
#pragma unroll
      for (int i = 0; i < 4; ++i) {
        if (i == j) continue;
        const float c = cf[i][j];
#pragma unroll
        for (int r = 0; r < 4; ++r) oacc[i][r] += c * vv[r];
      }
    }

    // ---- phase E: store ----
#pragma unroll
    for (int i = 0; i < 4; ++i) {
      const unsigned o = outbase + ((unsigned)i << 7) + (unsigned)bofs;
      __builtin_nontemporal_store(oacc[i], (floatx4*)(out + o));
    }

    // ---- stage next head's slice (single buffer: bar, gload_lds, bar) ----
    if (h < 7) {
      __syncthreads();                       // all reads of wlds done
      const bf16_t* wsrc = wt + (unsigned)(h + 1) * HSLICE;
#pragma unroll
      for (int q = 0; q < 6; ++q) {
        const unsigned off = ((unsigned)tid << 3) + ((unsigned)q << 12);
        stage16(wsrc + off, &wlds[off]);
      }
      __syncthreads();                       // vmcnt(0) drain + barrier: writes visible
    }
  }
}

extern "C" void kernel_launch(void* const* d_in, const int* in_sizes, int n_in,
                              void* d_out, int out_size, void* d_ws, size_t ws_size,
                              hipStream_t stream) {
  const float* x  = (const float*)d_in[0];
  const float* wq = (const float*)d_in[1];
  const float* bq = (const float*)d_in[2];
  const float* wk = (const float*)d_in[3];
  const float* bk = (const float*)d_in[4];
  const float* wv = (const float*)d_in[5];
  const float* bv = (const float*)d_in[6];
  const float* aw = (const float*)d_in[7];
  float* out = (float*)d_out;
  bf16_t* wt = (bf16_t*)d_ws;    // 8 head-slices x 24576 bf16 = 384 KiB

  transpose_w<<<dim3(192), dim3(256), 0, stream>>>(wq, wk, wv, wt);

  fused_attn<<<dim3(NBLK), dim3(512), 0, stream>>>(x, wt, bq, bk, bv, aw, out);
}

// Round 7
// 454.475 us; speedup vs baseline: 1.0209x; 1.0209x over previous
//
#include <hip/hip_runtime.h>
#include <hip/hip_bf16.h>

typedef __bf16 bf16_t;
typedef bf16_t bf16x8 __attribute__((ext_vector_type(8)));
typedef float  floatx4 __attribute__((ext_vector_type(4)));

#define NB    32
#define NV    207
#define NL    12
#define NROW  2484            // NV*NL rows per batch
#define TOTROW (NROW * NB)    // 79488
#define RPB   128             // rows per block (8 waves x 16)
#define NBLK  (TOTROW / RPB)  // 621 exactly, no tail
#define HSLICE 24576          // elems per head slice (12 mats x 16 rows x 128)
#define LDSPAD 28672          // pad LDS alloc to 57344 B -> exactly 2 blocks/CU

// ---- kernel 0: transpose + permute fp32 W[comp][d][e] -> bf16 wt in
// HEAD-SLICE FRAGMENT ORDER: wt[h*24576 + slot*8 + j], slot = mat*256 + k*64
// + quad*16 + l16, value = W[d = k*32+quad*8+j][e = h*16+l16].
// This makes the fused kernel's global staging address == its LDS offset.
__global__ __launch_bounds__(256)
void transpose_w(const float* __restrict__ wq,
                 const float* __restrict__ wk,
                 const float* __restrict__ wv,
                 bf16_t* __restrict__ wt) {
  __shared__ float t[32][33];
  const int mat  = blockIdx.x >> 4;          // 0..11
  const int tile = blockIdx.x & 15;          // 4x4 tiles of 32x32
  const int td = (tile >> 2) << 5;           // d-tile origin
  const int te = (tile & 3) << 5;            // e-tile origin
  const float* src = (mat < 4) ? wq : ((mat < 8) ? wk : wv);
  src += ((mat & 3) << 14);
  const int c  = threadIdx.x & 31;
  const int r0 = threadIdx.x >> 5;           // 0..7
#pragma unroll
  for (int rr = 0; rr < 4; ++rr) {
    const int r = r0 + (rr << 3);
    t[r][c] = src[((td + r) << 7) + te + c]; // read W[d][e], coalesced in e
  }
  __syncthreads();
#pragma unroll
  for (int rr = 0; rr < 4; ++rr) {
    const int r = r0 + (rr << 3);
    const int e = te + r, d = td + c;
    const int slot = (mat << 8) + ((d >> 5) << 6) + (((d >> 3) & 3) << 4) + (e & 15);
    wt[(e >> 4) * HSLICE + (slot << 3) + (d & 7)] = (bf16_t)t[c][r];
  }
}

__device__ __forceinline__ bf16x8 ldf8(const float* p) {
  floatx4 a = *(const floatx4*)p;
  floatx4 b = *(const floatx4*)(p + 4);
  bf16x8 r;
  r[0] = (bf16_t)a[0]; r[1] = (bf16_t)a[1]; r[2] = (bf16_t)a[2]; r[3] = (bf16_t)a[3];
  r[4] = (bf16_t)b[0]; r[5] = (bf16_t)b[1]; r[6] = (bf16_t)b[2]; r[7] = (bf16_t)b[3];
  return r;
}

__device__ __forceinline__ float bcast(float v) {
  return __uint_as_float(__builtin_amdgcn_readfirstlane(__float_as_uint(v)));
}

// global -> LDS direct (0 VGPRs), 16B per lane; dest is lane-linear (stride 16B).
__device__ __forceinline__ void stage16(const bf16_t* g, bf16_t* l) {
  __builtin_amdgcn_global_load_lds(
      (const __attribute__((address_space(1))) unsigned int*)g,
      (__attribute__((address_space(3))) unsigned int*)l, 16, 0, 0);
}

// Block = 8 waves x 16 rows = 128 rows, all 4 components, all 8 heads.
// x fragments in regs for the whole kernel (read ONCE). Per head: 48 KB
// fragment-ordered weight slice staged via global_load_lds, single buffer.
//
// REGISTER-ALLOCATOR STEERING (rounds 3-6 finding): the RA's occupancy
// target comes from the LDS limit. 48 KB -> 3 blocks/CU -> 6 waves/EU
// target -> RA squeezes to 64 VGPR WITH SPILLS (WRITE_SIZE 258 MB vs
// 163 MB real output). Padding LDS to 56 KB caps residency at 2 blocks/CU
// -> target 4 waves/EU -> 128-VGPR budget -> our ~115-reg body fits clean.
// __launch_bounds__(512,4) = hard 128 cap so 2-block residency is never lost.
__global__ __launch_bounds__(512, 4)
void fused_attn(const float* __restrict__ x,
                const bf16_t* __restrict__ wt,
                const float* __restrict__ bq,
                const float* __restrict__ bk,
                const float* __restrict__ bv,
                const float* __restrict__ aw,
                float* __restrict__ out) {
  __shared__ bf16_t wlds[LDSPAD];            // 57344 B alloc; only HSLICE used

  const int tid  = threadIdx.x;
  const int wid  = tid >> 6;
  const int lane = tid & 63;
  const int quad = lane >> 4;
  const int l16  = lane & 15;

  const int g = blockIdx.x * RPB + (wid << 4) + l16;   // global output row, < 79488
  const int b = g / NROW;
  const int n = g - b * NROW;
  const int v = n % NV;
  const int l = n / NV;
  const unsigned qkvbase = (((unsigned)b * NROW + (unsigned)(v * NL + l)) << 9); // attn source row
  const unsigned outbase = ((unsigned)g << 9);                                   // residual/store row

  // ---- x fragments for all 4 components, held in regs all kernel (64 VGPR) ----
  bf16x8 bx[4][4];
#pragma unroll
  for (int c = 0; c < 4; ++c) {
    const float* xp = x + qkvbase + (c << 7) + (quad << 3);
#pragma unroll
    for (int k = 0; k < 4; ++k) bx[c][k] = ldf8(xp + (k << 5));
  }

  // ---- stage head-0 slice: LDS offset == global offset (fragment order) ----
#pragma unroll
  for (int q = 0; q < 6; ++q) {
    const unsigned off = ((unsigned)tid << 3) + ((unsigned)q << 12);
    stage16(wt + off, &wlds[off]);
  }

  // ---- normalized subset weights (uniform -> SGPR) ----
  float pw[4][7];
#pragma unroll
  for (int i = 0; i < 4; ++i) {
    float sum = 0.f;
#pragma unroll
    for (int t = 0; t < 7; ++t) { pw[i][t] = __expf(aw[i * 8 + 1 + t]); sum += pw[i][t]; }
    const float inv = __builtin_amdgcn_rcpf(sum);
#pragma unroll
    for (int t = 0; t < 7; ++t) pw[i][t] = bcast(pw[i][t] * inv);
  }

  __syncthreads();   // drains vmcnt (gload_lds) then barrier

  const bf16_t* lbase = wlds + (lane << 3);

  // ---- head loop ----
  for (int h = 0; h < 8; ++h) {
    const int bofs = (h << 4) + (quad << 2);

    // ---- phase A: Q projections (mats 0..3) ----
    floatx4 QQ[4];
#pragma unroll
    for (int c = 0; c < 4; ++c) {
      floatx4 acc = *(const floatx4*)(bq + (c << 7) + bofs);
#pragma unroll
      for (int k = 0; k < 4; ++k)
        acc = __builtin_amdgcn_mfma_f32_16x16x32_bf16(
                *(const bf16x8*)(lbase + (((c << 2) + k) << 9)), bx[c][k], acc, 0, 0, 0);
      QQ[c] = acc;
    }

    // ---- phase B: stream K_j (mats 4..7), scores ee[i][j] ----
    float ee[4][4];
#pragma unroll
    for (int j = 0; j < 4; ++j) {
      floatx4 kk = *(const floatx4*)(bk + (j << 7) + bofs);
#pragma unroll
      for (int k = 0; k < 4; ++k)
        kk = __builtin_amdgcn_mfma_f32_16x16x32_bf16(
               *(const bf16x8*)(lbase + ((((4 + j) << 2) + k) << 9)), bx[j][k], kk, 0, 0, 0);
#pragma unroll
      for (int i = 0; i < 4; ++i) {
        if (i == j) continue;
        float p = QQ[i][0] * kk[0];
        p += QQ[i][1] * kk[1];
        p += QQ[i][2] * kk[2];
        p += QQ[i][3] * kk[3];
        p += __shfl_xor(p, 16);
        p += __shfl_xor(p, 32);
        ee[i][j] = __expf(p * 0.25f);
      }
    }

    // ---- phase C: subset-softmax coefficients cf[i][j] ----
    float cf[4][4];
#pragma unroll
    for (int i = 0; i < 4; ++i) {
      const int ja = (i == 0) ? 1 : 0;
      const int jb = (i < 2) ? 2 : 1;
      const int jc = (i < 3) ? 3 : 2;
      const float* w = pw[i];
      const float ea = ee[i][ja], eb = ee[i][jb], ec = ee[i][jc];
      const float dab = ea + eb, dac = ea + ec, dbc = eb + ec, dabc = dab + ec;
      const float r3 = w[2] * __builtin_amdgcn_rcpf(dbc);
      const float r5 = w[4] * __builtin_amdgcn_rcpf(dac);
      const float r6 = w[5] * __builtin_amdgcn_rcpf(dab);
      const float r7 = w[6] * __builtin_amdgcn_rcpf(dabc);
      cf[i][ja] = w[3] + ea * (r5 + r6 + r7);
      cf[i][jb] = w[1] + eb * (r3 + r6 + r7);
      cf[i][jc] = w[0] + ec * (r3 + r5 + r7);
    }

    // ---- phase D: residual load + stream V_j (mats 8..11), weighted combine ----
    floatx4 oacc[4];
#pragma unroll
    for (int i = 0; i < 4; ++i)
      oacc[i] = *(const floatx4*)(x + outbase + ((unsigned)i << 7) + (unsigned)bofs);

#pragma unroll
    for (int j = 0; j < 4; ++j) {
      floatx4 vv = *(const floatx4*)(bv + (j << 7) + bofs);
#pragma unroll
      for (int k = 0; k < 4; ++k)
        vv = __builtin_amdgcn_mfma_f32_16x16x32_bf16(
               *(const bf16x8*)(lbase + ((((8 + j) << 2) + k) << 9)), bx[j][k], vv, 0, 0, 0);
#pragma unroll
      for (int i = 0; i < 4; ++i) {
        if (i == j) continue;
        const float c = cf[i][j];
#pragma unroll
        for (int r = 0; r < 4; ++r) oacc[i][r] += c * vv[r];
      }
    }

    // ---- phase E: store ----
#pragma unroll
    for (int i = 0; i < 4; ++i) {
      const unsigned o = outbase + ((unsigned)i << 7) + (unsigned)bofs;
      __builtin_nontemporal_store(oacc[i], (floatx4*)(out + o));
    }

    // ---- stage next head's slice (single buffer: bar, gload_lds, bar) ----
    if (h < 7) {
      __syncthreads();                       // all reads of wlds done
      const bf16_t* wsrc = wt + (unsigned)(h + 1) * HSLICE;
#pragma unroll
      for (int q = 0; q < 6; ++q) {
        const unsigned off = ((unsigned)tid << 3) + ((unsigned)q << 12);
        stage16(wsrc + off, &wlds[off]);
      }
      __syncthreads();                       // vmcnt(0) drain + barrier: writes visible
    }
  }
}

extern "C" void kernel_launch(void* const* d_in, const int* in_sizes, int n_in,
                              void* d_out, int out_size, void* d_ws, size_t ws_size,
                              hipStream_t stream) {
  const float* x  = (const float*)d_in[0];
  const float* wq = (const float*)d_in[1];
  const float* bq = (const float*)d_in[2];
  const float* wk = (const float*)d_in[3];
  const float* bk = (const float*)d_in[4];
  const float* wv = (const float*)d_in[5];
  const float* bv = (const float*)d_in[6];
  const float* aw = (const float*)d_in[7];
  float* out = (float*)d_out;
  bf16_t* wt = (bf16_t*)d_ws;    // 8 head-slices x 24576 bf16 = 384 KiB

  transpose_w<<<dim3(192), dim3(256), 0, stream>>>(wq, wk, wv, wt);

  fused_attn<<<dim3(NBLK), dim3(512), 0, stream>>>(x, wt, bq, bk, bv, aw, out);
}

// Round 8
// 406.456 us; speedup vs baseline: 1.1415x; 1.1181x over previous
//
#include <hip/hip_runtime.h>
#include <hip/hip_bf16.h>

typedef __bf16 bf16_t;
typedef bf16_t bf16x8 __attribute__((ext_vector_type(8)));
typedef float  floatx4 __attribute__((ext_vector_type(4)));

#define NB    32
#define NV    207
#define NL    12
#define NROW  2484            // NV*NL rows per batch
#define TOTROW (NROW * NB)    // 79488
#define RPB   128             // rows per block (8 waves x 16)
#define NBLK  (TOTROW / RPB)  // 621 exactly, no tail
#define HSLICE 24576          // elems per head slice (12 mats x 16 rows x 128)
#define LDSPAD 28672          // pad LDS alloc to 57344 B -> exactly 2 blocks/CU

// ---- kernel 0: transpose + permute fp32 W[comp][d][e] -> bf16 wt in
// HEAD-SLICE FRAGMENT ORDER: wt[h*24576 + slot*8 + j], slot = mat*256 + k*64
// + quad*16 + l16, value = W[d = k*32+quad*8+j][e = h*16+l16].
// This makes the fused kernel's global staging address == its LDS offset.
__global__ __launch_bounds__(256)
void transpose_w(const float* __restrict__ wq,
                 const float* __restrict__ wk,
                 const float* __restrict__ wv,
                 bf16_t* __restrict__ wt) {
  __shared__ float t[32][33];
  const int mat  = blockIdx.x >> 4;          // 0..11
  const int tile = blockIdx.x & 15;          // 4x4 tiles of 32x32
  const int td = (tile >> 2) << 5;           // d-tile origin
  const int te = (tile & 3) << 5;            // e-tile origin
  const float* src = (mat < 4) ? wq : ((mat < 8) ? wk : wv);
  src += ((mat & 3) << 14);
  const int c  = threadIdx.x & 31;
  const int r0 = threadIdx.x >> 5;           // 0..7
#pragma unroll
  for (int rr = 0; rr < 4; ++rr) {
    const int r = r0 + (rr << 3);
    t[r][c] = src[((td + r) << 7) + te + c]; // read W[d][e], coalesced in e
  }
  __syncthreads();
#pragma unroll
  for (int rr = 0; rr < 4; ++rr) {
    const int r = r0 + (rr << 3);
    const int e = te + r, d = td + c;
    const int slot = (mat << 8) + ((d >> 5) << 6) + (((d >> 3) & 3) << 4) + (e & 15);
    wt[(e >> 4) * HSLICE + (slot << 3) + (d & 7)] = (bf16_t)t[c][r];
  }
}

__device__ __forceinline__ bf16x8 ldf8(const float* p) {
  floatx4 a = *(const floatx4*)p;
  floatx4 b = *(const floatx4*)(p + 4);
  bf16x8 r;
  r[0] = (bf16_t)a[0]; r[1] = (bf16_t)a[1]; r[2] = (bf16_t)a[2]; r[3] = (bf16_t)a[3];
  r[4] = (bf16_t)b[0]; r[5] = (bf16_t)b[1]; r[6] = (bf16_t)b[2]; r[7] = (bf16_t)b[3];
  return r;
}

__device__ __forceinline__ float bcast(float v) {
  return __uint_as_float(__builtin_amdgcn_readfirstlane(__float_as_uint(v)));
}

// global -> LDS direct (0 VGPRs), 16B per lane; dest is lane-linear (stride 16B).
__device__ __forceinline__ void stage16(const bf16_t* g, bf16_t* l) {
  __builtin_amdgcn_global_load_lds(
      (const __attribute__((address_space(1))) unsigned int*)g,
      (__attribute__((address_space(3))) unsigned int*)l, 16, 0, 0);
}

// Block = 8 waves x 16 rows = 128 rows, all 4 components, all 8 heads.
// x fragments in regs for the whole kernel (read ONCE). Per head: 48 KB
// fragment-ordered weight slice staged via global_load_lds, single buffer.
//
// LAUNCH-BOUNDS SEMANTICS (rounds 3-7 finding): on this toolchain the 2nd
// __launch_bounds__ arg behaves like CUDA's min-BLOCKS-per-CU:
//   (512,2) -> 4 waves/EU -> 128-VGPR budget -> clean alloc (round 3: VGPR=128, no spill)
//   (512,4) -> 8 waves/EU -> 64-VGPR budget  -> spills (rounds 4/6/7: VGPR=64,
//              WRITE_SIZE 258 MB vs 163 MB real output)
// So: (512,2) + LDS padded to 56 KB = exactly 2 blocks/CU co-resident AND a
// 128-VGPR budget that fits this ~115-reg body with zero spill.
__global__ __launch_bounds__(512, 2)
void fused_attn(const float* __restrict__ x,
                const bf16_t* __restrict__ wt,
                const float* __restrict__ bq,
                const float* __restrict__ bk,
                const float* __restrict__ bv,
                const float* __restrict__ aw,
                float* __restrict__ out) {
  __shared__ bf16_t wlds[LDSPAD];            // 57344 B alloc; only HSLICE used

  const int tid  = threadIdx.x;
  const int wid  = tid >> 6;
  const int lane = tid & 63;
  const int quad = lane >> 4;
  const int l16  = lane & 15;

  const int g = blockIdx.x * RPB + (wid << 4) + l16;   // global output row, < 79488
  const int b = g / NROW;
  const int n = g - b * NROW;
  const int v = n % NV;
  const int l = n / NV;
  const unsigned qkvbase = (((unsigned)b * NROW + (unsigned)(v * NL + l)) << 9); // attn source row
  const unsigned outbase = ((unsigned)g << 9);                                   // residual/store row

  // ---- x fragments for all 4 components, held in regs all kernel (64 VGPR) ----
  bf16x8 bx[4][4];
#pragma unroll
  for (int c = 0; c < 4; ++c) {
    const float* xp = x + qkvbase + (c << 7) + (quad << 3);
#pragma unroll
    for (int k = 0; k < 4; ++k) bx[c][k] = ldf8(xp + (k << 5));
  }

  // ---- stage head-0 slice: LDS offset == global offset (fragment order) ----
#pragma unroll
  for (int q = 0; q < 6; ++q) {
    const unsigned off = ((unsigned)tid << 3) + ((unsigned)q << 12);
    stage16(wt + off, &wlds[off]);
  }

  // ---- normalized subset weights (uniform -> SGPR) ----
  float pw[4][7];
#pragma unroll
  for (int i = 0; i < 4; ++i) {
    float sum = 0.f;
#pragma unroll
    for (int t = 0; t < 7; ++t) { pw[i][t] = __expf(aw[i * 8 + 1 + t]); sum += pw[i][t]; }
    const float inv = __builtin_amdgcn_rcpf(sum);
#pragma unroll
    for (int t = 0; t < 7; ++t) pw[i][t] = bcast(pw[i][t] * inv);
  }

  __syncthreads();   // drains vmcnt (gload_lds) then barrier

  const bf16_t* lbase = wlds + (lane << 3);

  // ---- head loop ----
  for (int h = 0; h < 8; ++h) {
    const int bofs = (h << 4) + (quad << 2);

    // ---- phase A: Q projections (mats 0..3) ----
    floatx4 QQ[4];
#pragma unroll
    for (int c = 0; c < 4; ++c) {
      floatx4 acc = *(const floatx4*)(bq + (c << 7) + bofs);
#pragma unroll
      for (int k = 0; k < 4; ++k)
        acc = __builtin_amdgcn_mfma_f32_16x16x32_bf16(
                *(const bf16x8*)(lbase + (((c << 2) + k) << 9)), bx[c][k], acc, 0, 0, 0);
      QQ[c] = acc;
    }

    // ---- phase B: stream K_j (mats 4..7), scores ee[i][j] ----
    float ee[4][4];
#pragma unroll
    for (int j = 0; j < 4; ++j) {
      floatx4 kk = *(const floatx4*)(bk + (j << 7) + bofs);
#pragma unroll
      for (int k = 0; k < 4; ++k)
        kk = __builtin_amdgcn_mfma_f32_16x16x32_bf16(
               *(const bf16x8*)(lbase + ((((4 + j) << 2) + k) << 9)), bx[j][k], kk, 0, 0, 0);
#pragma unroll
      for (int i = 0; i < 4; ++i) {
        if (i == j) continue;
        float p = QQ[i][0] * kk[0];
        p += QQ[i][1] * kk[1];
        p += QQ[i][2] * kk[2];
        p += QQ[i][3] * kk[3];
        p += __shfl_xor(p, 16);
        p += __shfl_xor(p, 32);
        ee[i][j] = __expf(p * 0.25f);
      }
    }

    // ---- phase C: subset-softmax coefficients cf[i][j] ----
    float cf[4][4];
#pragma unroll
    for (int i = 0; i < 4; ++i) {
      const int ja = (i == 0) ? 1 : 0;
      const int jb = (i < 2) ? 2 : 1;
      const int jc = (i < 3) ? 3 : 2;
      const float* w = pw[i];
      const float ea = ee[i][ja], eb = ee[i][jb], ec = ee[i][jc];
      const float dab = ea + eb, dac = ea + ec, dbc = eb + ec, dabc = dab + ec;
      const float r3 = w[2] * __builtin_amdgcn_rcpf(dbc);
      const float r5 = w[4] * __builtin_amdgcn_rcpf(dac);
      const float r6 = w[5] * __builtin_amdgcn_rcpf(dab);
      const float r7 = w[6] * __builtin_amdgcn_rcpf(dabc);
      cf[i][ja] = w[3] + ea * (r5 + r6 + r7);
      cf[i][jb] = w[1] + eb * (r3 + r6 + r7);
      cf[i][jc] = w[0] + ec * (r3 + r5 + r7);
    }

    // ---- phase D: residual load + stream V_j (mats 8..11), weighted combine ----
    floatx4 oacc[4];
#pragma unroll
    for (int i = 0; i < 4; ++i)
      oacc[i] = *(const floatx4*)(x + outbase + ((unsigned)i << 7) + (unsigned)bofs);

#pragma unroll
    for (int j = 0; j < 4; ++j) {
      floatx4 vv = *(const floatx4*)(bv + (j << 7) + bofs);
#pragma unroll
      for (int k = 0; k < 4; ++k)
        vv = __builtin_amdgcn_mfma_f32_16x16x32_bf16(
               *(const bf16x8*)(lbase + ((((8 + j) << 2) + k) << 9)), bx[j][k], vv, 0, 0, 0);
#pragma unroll
      for (int i = 0; i < 4; ++i) {
        if (i == j) continue;
        const float c = cf[i][j];
#pragma unroll
        for (int r = 0; r < 4; ++r) oacc[i][r] += c * vv[r];
      }
    }

    // ---- phase E: store ----
#pragma unroll
    for (int i = 0; i < 4; ++i) {
      const unsigned o = outbase + ((unsigned)i << 7) + (unsigned)bofs;
      __builtin_nontemporal_store(oacc[i], (floatx4*)(out + o));
    }

    // ---- stage next head's slice (single buffer: bar, gload_lds, bar) ----
    if (h < 7) {
      __syncthreads();                       // all reads of wlds done
      const bf16_t* wsrc = wt + (unsigned)(h + 1) * HSLICE;
#pragma unroll
      for (int q = 0; q < 6; ++q) {
        const unsigned off = ((unsigned)tid << 3) + ((unsigned)q << 12);
        stage16(wsrc + off, &wlds[off]);
      }
      __syncthreads();                       // vmcnt(0) drain + barrier: writes visible
    }
  }
}

extern "C" void kernel_launch(void* const* d_in, const int* in_sizes, int n_in,
                              void* d_out, int out_size, void* d_ws, size_t ws_size,
                              hipStream_t stream) {
  const float* x  = (const float*)d_in[0];
  const float* wq = (const float*)d_in[1];
  const float* bq = (const float*)d_in[2];
  const float* wk = (const float*)d_in[3];
  const float* bk = (const float*)d_in[4];
  const float* wv = (const float*)d_in[5];
  const float* bv = (const float*)d_in[6];
  const float* aw = (const float*)d_in[7];
  float* out = (float*)d_out;
  bf16_t* wt = (bf16_t*)d_ws;    // 8 head-slices x 24576 bf16 = 384 KiB

  transpose_w<<<dim3(192), dim3(256), 0, stream>>>(wq, wk, wv, wt);

  fused_attn<<<dim3(NBLK), dim3(512), 0, stream>>>(x, wt, bq, bk, bv, aw, out);
}